// Round 10
// baseline (81.236 us; speedup 1.0000x reference)
//
#include <hip/hip_runtime.h>

#define BB 4
#define NN 8192
#define MM 2048
#define CC 64
#define KK 16

// ---------------------------------------------------------------------------
// Kernel 1: transpose features [B,C,N] -> featsT [B,N,C] so per-neighbor
// feature gathers are contiguous 256B rows.
// ---------------------------------------------------------------------------
__global__ __launch_bounds__(256) void transpose_feats(const float* __restrict__ f,
                                                       float* __restrict__ ft) {
    __shared__ float tile[64][65];
    const int b    = blockIdx.y;
    const int n0   = blockIdx.x * 64;
    const int lane = threadIdx.x & 63;
    const int grp  = threadIdx.x >> 6;  // 0..3
    const float* src = f + (size_t)b * CC * NN;
    float* dst       = ft + (size_t)b * NN * CC;
#pragma unroll
    for (int it = 0; it < 16; ++it) {
        const int c = grp + it * 4;                    // channel
        tile[c][lane] = src[c * NN + n0 + lane];       // coalesced along N
    }
    __syncthreads();
#pragma unroll
    for (int it = 0; it < 16; ++it) {
        const int nl = grp + it * 4;                   // local point
        dst[(size_t)(n0 + nl) * CC + lane] = tile[lane][nl];  // coalesced along C
    }
}

// ---------------------------------------------------------------------------
// VERIFIED (round 7, absmax=0): reference rounding = XLA-CPU FPOpFusion::Fast:
//   qq  = fma(qz,qz, fma(qy,qy, qx*qx))
//   pp  = fma(pz,pz, fma(py,py, px*px))
//   dot = fma(qz,pz, fma(qy,py, qx*px))
//   d   = (qq - 2*dot) + pp
// DO NOT CHANGE these two functions.
// ---------------------------------------------------------------------------
__device__ __forceinline__ float sq3(float x, float y, float z) {
    return __fmaf_rn(z, z, __fmaf_rn(y, y, __fmul_rn(x, x)));
}
__device__ __forceinline__ float dist32(float qx, float qy, float qz, float qq,
                                        float px, float py, float pz, float pp) {
    float dot = __fmaf_rn(qz, pz, __fmaf_rn(qy, py, __fmul_rn(qx, px)));
    return __fadd_rn(__fsub_rn(qq, __fmul_rn(2.0f, dot)), pp);
}

// ---------------------------------------------------------------------------
// Kernel 2 (v2): block = 4 queries, 4 waves; wave w scans point range
// [w*2048, (w+1)*2048). 2048 blocks -> 32 waves/CU (was 8).
//   Phase A: per-lane min over its 32 points; per-query bitonic-64 sort of
//            lane minima; top-16 per (query,wave) -> LDS.
//   tau:     wave q merges 4x16 values, bitonic-64 -> exact 16th smallest of
//            the 256 partial minima (valid upper bound on true D16: the 16
//            smallest partial minima come from >=16 distinct points).
//   Phase B: rescan own range, append idx with d <= tau[q] to block-shared
//            candidate buffer (LDS atomics, ~17-20 typical, cap 64).
//   Phase C: wave q sorts query q's candidates on (d, idx) -> top-16 in
//            lax.top_k stable order.
//   Write:   wave g handles channels c = g+4t; per (c): 64 lanes (4q x 16k)
//            store 256B contiguous.
// ---------------------------------------------------------------------------
__global__ __launch_bounds__(256) void knn_group2(const float* __restrict__ points,
                                                  const float* __restrict__ newp,
                                                  const float* __restrict__ feat,
                                                  const int fsN, const int fsC,
                                                  float* __restrict__ out) {
    const int wave = threadIdx.x >> 6;
    const int lane = threadIdx.x & 63;
    const int qbase = blockIdx.x * 4;               // 4 queries per block
    const int b  = qbase / MM;
    const int m0 = qbase % MM;

    const float* px_ = points + (size_t)b * 3 * NN;
    const float* py_ = px_ + NN;
    const float* pz_ = py_ + NN;
    const float* q_  = newp + (size_t)b * 3 * MM;

    float qx[4], qy[4], qz[4], qq[4];
#pragma unroll
    for (int q = 0; q < 4; ++q) {
        qx[q] = q_[m0 + q];
        qy[q] = q_[MM + m0 + q];
        qz[q] = q_[2 * MM + m0 + q];
        qq[q] = sq3(qx[q], qy[q], qz[q]);
    }

    const float INF = __int_as_float(0x7f800000);
    const int base = wave * (NN / 4);               // this wave's point range

    __shared__ float s_top[4][4][16];   // [query][wave][rank]
    __shared__ float s_tau[4];
    __shared__ int   s_cnt[4];
    __shared__ int   s_i[4][64];
    __shared__ int   s_win[4][16];

    // ---- Phase A: per-lane min over 32 points (8 x 3 float4 loads) ----
    float m1[4] = {INF, INF, INF, INF};
#pragma unroll
    for (int j4 = 0; j4 < 8; ++j4) {
        const int ib = base + j4 * 256 + lane * 4;
        const float4 vx = *(const float4*)(px_ + ib);
        const float4 vy = *(const float4*)(py_ + ib);
        const float4 vz = *(const float4*)(pz_ + ib);
        const float pxa[4] = {vx.x, vx.y, vx.z, vx.w};
        const float pya[4] = {vy.x, vy.y, vy.z, vy.w};
        const float pza[4] = {vz.x, vz.y, vz.z, vz.w};
#pragma unroll
        for (int e = 0; e < 4; ++e) {
            const float px = pxa[e], py = pya[e], pz = pza[e];
            const float pp = sq3(px, py, pz);
#pragma unroll
            for (int q = 0; q < 4; ++q)
                m1[q] = fminf(m1[q], dist32(qx[q], qy[q], qz[q], qq[q], px, py, pz, pp));
        }
    }

    // ---- per-(query,wave) sorted top-16 of the 64 lane minima ----
#pragma unroll
    for (int q = 0; q < 4; ++q) {
        float v = m1[q];
#pragma unroll
        for (int k = 2; k <= 64; k <<= 1) {
#pragma unroll
            for (int j = k >> 1; j > 0; j >>= 1) {
                const float pv = __shfl_xor(v, j, 64);
                const bool keepMin = ((lane & j) == 0) == ((lane & k) == 0);
                v = keepMin ? fminf(v, pv) : fmaxf(v, pv);
            }
        }
        if (lane < 16) s_top[q][wave][lane] = v;
    }
    if (threadIdx.x < 4) s_cnt[threadIdx.x] = 0;
    __syncthreads();

    // ---- tau[q]: wave q merges 4 sorted-16 heads -> exact 16th of 256 ----
    {
        const int q = wave;
        float v = s_top[q][lane >> 4][lane & 15];
#pragma unroll
        for (int k = 2; k <= 64; k <<= 1) {
#pragma unroll
            for (int j = k >> 1; j > 0; j >>= 1) {
                const float pv = __shfl_xor(v, j, 64);
                const bool keepMin = ((lane & j) == 0) == ((lane & k) == 0);
                v = keepMin ? fminf(v, pv) : fmaxf(v, pv);
            }
        }
        if (lane == 15) s_tau[q] = v;
    }
    __syncthreads();
    float tau[4];
#pragma unroll
    for (int q = 0; q < 4; ++q) tau[q] = s_tau[q];

    // ---- Phase B: rescan own range, append candidates ----
#pragma unroll
    for (int j4 = 0; j4 < 8; ++j4) {
        const int ib = base + j4 * 256 + lane * 4;
        const float4 vx = *(const float4*)(px_ + ib);
        const float4 vy = *(const float4*)(py_ + ib);
        const float4 vz = *(const float4*)(pz_ + ib);
        const float pxa[4] = {vx.x, vx.y, vx.z, vx.w};
        const float pya[4] = {vy.x, vy.y, vy.z, vy.w};
        const float pza[4] = {vz.x, vz.y, vz.z, vz.w};
#pragma unroll
        for (int e = 0; e < 4; ++e) {
            const float px = pxa[e], py = pya[e], pz = pza[e];
            const float pp = sq3(px, py, pz);
#pragma unroll
            for (int q = 0; q < 4; ++q) {
                const float d = dist32(qx[q], qy[q], qz[q], qq[q], px, py, pz, pp);
                if (d <= tau[q]) {
                    const int pos = atomicAdd(&s_cnt[q], 1);
                    if (pos < 64) s_i[q][pos] = ib + e;
                }
            }
        }
    }
    __syncthreads();

    // ---- Phase C: wave q sorts query q's candidates on (d, idx) ----
    {
        const int q = wave;
        const int cnt = min(s_cnt[q], 64);
        float d = INF;
        int idx = 0x7fffffff;
        if (lane < cnt) {
            idx = s_i[q][lane];
            const float px = px_[idx], py = py_[idx], pz = pz_[idx];
            d = dist32(qx[q], qy[q], qz[q], qq[q], px, py, pz, sq3(px, py, pz));
        }
#pragma unroll
        for (int k = 2; k <= 64; k <<= 1) {
#pragma unroll
            for (int j = k >> 1; j > 0; j >>= 1) {
                const float pd = __shfl_xor(d, j, 64);
                const int   pi = __shfl_xor(idx, j, 64);
                const bool keepMin = ((lane & j) == 0) == ((lane & k) == 0);
                const bool pLess = (pd < d) || (pd == d && pi < idx);
                if (keepMin ? pLess : !pLess) { d = pd; idx = pi; }
            }
        }
        if (lane < KK) s_win[q][lane] = idx;
    }
    __syncthreads();

    // ---- Write: wave g handles channels c = g + 4t; 256B stores per c ----
    const int q2 = lane >> 4;
    const int kk = lane & 15;
    const int idx = s_win[q2][kk];
    const int m   = m0 + q2;

    float* ob = out + (size_t)b * (3 + CC) * MM * KK + (size_t)m * KK + kk;
    const size_t chs = (size_t)MM * KK;
    const float* fr = feat + (size_t)b * CC * NN + (size_t)idx * fsN;

#pragma unroll
    for (int t = 0; t < 17; ++t) {
        const int c = wave + t * 4;
        if (c < 3 + CC) {
            float val;
            if (c == 0)      val = __fsub_rn(px_[idx], qx[q2]);
            else if (c == 1) val = __fsub_rn(py_[idx], qy[q2]);
            else if (c == 2) val = __fsub_rn(pz_[idx], qz[q2]);
            else             val = fr[(size_t)(c - 3) * fsC];
            ob[(size_t)c * chs] = val;
        }
    }
}

extern "C" void kernel_launch(void* const* d_in, const int* in_sizes, int n_in,
                              void* d_out, int out_size, void* d_ws, size_t ws_size,
                              hipStream_t stream) {
    const float* points = (const float*)d_in[0];
    const float* newp   = (const float*)d_in[1];
    const float* feats  = (const float*)d_in[2];
    float* out = (float*)d_out;

    const size_t ftBytes = (size_t)BB * NN * CC * sizeof(float);
    if (ws_size >= ftBytes) {
        float* ft = (float*)d_ws;
        transpose_feats<<<dim3(NN / 64, BB), 256, 0, stream>>>(feats, ft);
        knn_group2<<<(BB * MM) / 4, 256, 0, stream>>>(points, newp, ft, CC, 1, out);
    } else {
        // Fallback: gather straight from [B,C,N] (strided) if ws is too small.
        knn_group2<<<(BB * MM) / 4, 256, 0, stream>>>(points, newp, feats, 1, NN, out);
    }
}

// Round 11
// 61.277 us; speedup vs baseline: 1.3257x; 1.3257x over previous
//
#include <hip/hip_runtime.h>

#define BB 4
#define NN 8192
#define MM 2048
#define CC 64
#define KK 16

// ---------------------------------------------------------------------------
// Kernel 1: transpose features [B,C,N] -> featsT [B,N,C] so per-neighbor
// feature gathers are contiguous 256B rows.
// ---------------------------------------------------------------------------
__global__ __launch_bounds__(256) void transpose_feats(const float* __restrict__ f,
                                                       float* __restrict__ ft) {
    __shared__ float tile[64][65];
    const int b    = blockIdx.y;
    const int n0   = blockIdx.x * 64;
    const int lane = threadIdx.x & 63;
    const int grp  = threadIdx.x >> 6;  // 0..3
    const float* src = f + (size_t)b * CC * NN;
    float* dst       = ft + (size_t)b * NN * CC;
#pragma unroll
    for (int it = 0; it < 16; ++it) {
        const int c = grp + it * 4;                    // channel
        tile[c][lane] = src[c * NN + n0 + lane];       // coalesced along N
    }
    __syncthreads();
#pragma unroll
    for (int it = 0; it < 16; ++it) {
        const int nl = grp + it * 4;                   // local point
        dst[(size_t)(n0 + nl) * CC + lane] = tile[lane][nl];  // coalesced along C
    }
}

// ---------------------------------------------------------------------------
// VERIFIED (round 7, absmax=0): reference rounding = XLA-CPU FPOpFusion::Fast:
//   qq  = fma(qz,qz, fma(qy,qy, qx*qx))
//   pp  = fma(pz,pz, fma(py,py, px*px))
//   dot = fma(qz,pz, fma(qy,py, qx*px))
//   d   = (qq - 2*dot) + pp
// DO NOT CHANGE these two functions.
// ---------------------------------------------------------------------------
__device__ __forceinline__ float sq3(float x, float y, float z) {
    return __fmaf_rn(z, z, __fmaf_rn(y, y, __fmul_rn(x, x)));
}
__device__ __forceinline__ float dist32(float qx, float qy, float qz, float qq,
                                        float px, float py, float pz, float pp) {
    float dot = __fmaf_rn(qz, pz, __fmaf_rn(qy, py, __fmul_rn(qx, px)));
    return __fadd_rn(__fsub_rn(qq, __fmul_rn(2.0f, dot)), pp);
}

// ---------------------------------------------------------------------------
// Kernel 2 (v3): v2 structure (block = 4 queries, 4 waves, wave scans a
// disjoint 2048-point range; exact tau via per-range top-16 merge), with:
//   - __launch_bounds__(256, 8): 8 blocks/CU -> allocator forced to <=64 VGPR
//     (v2's 84 VGPR silently capped residency; occupancy never materialized).
//   - #pragma unroll 2 on scan loops (full unroll caused the VGPR bloat).
// ---------------------------------------------------------------------------
__global__ __launch_bounds__(256, 8) void knn_group2(const float* __restrict__ points,
                                                     const float* __restrict__ newp,
                                                     const float* __restrict__ feat,
                                                     const int fsN, const int fsC,
                                                     float* __restrict__ out) {
    const int wave = threadIdx.x >> 6;
    const int lane = threadIdx.x & 63;
    const int qbase = blockIdx.x * 4;               // 4 queries per block
    const int b  = qbase / MM;
    const int m0 = qbase % MM;

    const float* px_ = points + (size_t)b * 3 * NN;
    const float* py_ = px_ + NN;
    const float* pz_ = py_ + NN;
    const float* q_  = newp + (size_t)b * 3 * MM;

    float qx[4], qy[4], qz[4], qq[4];
#pragma unroll
    for (int q = 0; q < 4; ++q) {
        qx[q] = q_[m0 + q];
        qy[q] = q_[MM + m0 + q];
        qz[q] = q_[2 * MM + m0 + q];
        qq[q] = sq3(qx[q], qy[q], qz[q]);
    }

    const float INF = __int_as_float(0x7f800000);
    const int base = wave * (NN / 4);               // this wave's point range

    __shared__ float s_top[4][4][16];   // [query][wave][rank]
    __shared__ float s_tau[4];
    __shared__ int   s_cnt[4];
    __shared__ int   s_i[4][64];
    __shared__ int   s_win[4][16];

    // ---- Phase A: per-lane min over 32 points (8 x 3 float4 loads) ----
    float m1[4] = {INF, INF, INF, INF};
#pragma unroll 2
    for (int j4 = 0; j4 < 8; ++j4) {
        const int ib = base + j4 * 256 + lane * 4;
        const float4 vx = *(const float4*)(px_ + ib);
        const float4 vy = *(const float4*)(py_ + ib);
        const float4 vz = *(const float4*)(pz_ + ib);
        const float pxa[4] = {vx.x, vx.y, vx.z, vx.w};
        const float pya[4] = {vy.x, vy.y, vy.z, vy.w};
        const float pza[4] = {vz.x, vz.y, vz.z, vz.w};
#pragma unroll
        for (int e = 0; e < 4; ++e) {
            const float px = pxa[e], py = pya[e], pz = pza[e];
            const float pp = sq3(px, py, pz);
#pragma unroll
            for (int q = 0; q < 4; ++q)
                m1[q] = fminf(m1[q], dist32(qx[q], qy[q], qz[q], qq[q], px, py, pz, pp));
        }
    }

    // ---- per-(query,wave) sorted top-16 of the 64 lane minima ----
#pragma unroll 1
    for (int q = 0; q < 4; ++q) {
        float v = m1[q];
#pragma unroll
        for (int k = 2; k <= 64; k <<= 1) {
#pragma unroll
            for (int j = k >> 1; j > 0; j >>= 1) {
                const float pv = __shfl_xor(v, j, 64);
                const bool keepMin = ((lane & j) == 0) == ((lane & k) == 0);
                v = keepMin ? fminf(v, pv) : fmaxf(v, pv);
            }
        }
        if (lane < 16) s_top[q][wave][lane] = v;
    }
    if (threadIdx.x < 4) s_cnt[threadIdx.x] = 0;
    __syncthreads();

    // ---- tau[q]: wave q merges 4 sorted-16 heads -> exact 16th of 256 ----
    {
        const int q = wave;
        float v = s_top[q][lane >> 4][lane & 15];
#pragma unroll
        for (int k = 2; k <= 64; k <<= 1) {
#pragma unroll
            for (int j = k >> 1; j > 0; j >>= 1) {
                const float pv = __shfl_xor(v, j, 64);
                const bool keepMin = ((lane & j) == 0) == ((lane & k) == 0);
                v = keepMin ? fminf(v, pv) : fmaxf(v, pv);
            }
        }
        if (lane == 15) s_tau[q] = v;
    }
    __syncthreads();
    float tau[4];
#pragma unroll
    for (int q = 0; q < 4; ++q) tau[q] = s_tau[q];

    // ---- Phase B: rescan own range, append candidates ----
#pragma unroll 2
    for (int j4 = 0; j4 < 8; ++j4) {
        const int ib = base + j4 * 256 + lane * 4;
        const float4 vx = *(const float4*)(px_ + ib);
        const float4 vy = *(const float4*)(py_ + ib);
        const float4 vz = *(const float4*)(pz_ + ib);
        const float pxa[4] = {vx.x, vx.y, vx.z, vx.w};
        const float pya[4] = {vy.x, vy.y, vy.z, vy.w};
        const float pza[4] = {vz.x, vz.y, vz.z, vz.w};
#pragma unroll
        for (int e = 0; e < 4; ++e) {
            const float px = pxa[e], py = pya[e], pz = pza[e];
            const float pp = sq3(px, py, pz);
#pragma unroll
            for (int q = 0; q < 4; ++q) {
                const float d = dist32(qx[q], qy[q], qz[q], qq[q], px, py, pz, pp);
                if (d <= tau[q]) {
                    const int pos = atomicAdd(&s_cnt[q], 1);
                    if (pos < 64) s_i[q][pos] = ib + e;
                }
            }
        }
    }
    __syncthreads();

    // ---- Phase C: wave q sorts query q's candidates on (d, idx) ----
    {
        const int q = wave;
        const int cnt = min(s_cnt[q], 64);
        float d = INF;
        int idx = 0x7fffffff;
        if (lane < cnt) {
            idx = s_i[q][lane];
            const float px = px_[idx], py = py_[idx], pz = pz_[idx];
            d = dist32(qx[q], qy[q], qz[q], qq[q], px, py, pz, sq3(px, py, pz));
        }
#pragma unroll
        for (int k = 2; k <= 64; k <<= 1) {
#pragma unroll
            for (int j = k >> 1; j > 0; j >>= 1) {
                const float pd = __shfl_xor(d, j, 64);
                const int   pi = __shfl_xor(idx, j, 64);
                const bool keepMin = ((lane & j) == 0) == ((lane & k) == 0);
                const bool pLess = (pd < d) || (pd == d && pi < idx);
                if (keepMin ? pLess : !pLess) { d = pd; idx = pi; }
            }
        }
        if (lane < KK) s_win[q][lane] = idx;
    }
    __syncthreads();

    // ---- Write: wave g handles channels c = g + 4t; 256B stores per c ----
    const int q2 = lane >> 4;
    const int kk = lane & 15;
    const int idx = s_win[q2][kk];

    float* ob = out + (size_t)b * (3 + CC) * MM * KK + (size_t)(m0 + q2) * KK + kk;
    const size_t chs = (size_t)MM * KK;
    const float* fr = feat + (size_t)b * CC * NN + (size_t)idx * fsN;

#pragma unroll 1
    for (int t = 0; t < 17; ++t) {
        const int c = wave + t * 4;
        if (c < 3 + CC) {
            float val;
            if (c == 0)      val = __fsub_rn(px_[idx], qx[q2]);
            else if (c == 1) val = __fsub_rn(py_[idx], qy[q2]);
            else if (c == 2) val = __fsub_rn(pz_[idx], qz[q2]);
            else             val = fr[(size_t)(c - 3) * fsC];
            ob[(size_t)c * chs] = val;
        }
    }
}

extern "C" void kernel_launch(void* const* d_in, const int* in_sizes, int n_in,
                              void* d_out, int out_size, void* d_ws, size_t ws_size,
                              hipStream_t stream) {
    const float* points = (const float*)d_in[0];
    const float* newp   = (const float*)d_in[1];
    const float* feats  = (const float*)d_in[2];
    float* out = (float*)d_out;

    const size_t ftBytes = (size_t)BB * NN * CC * sizeof(float);
    if (ws_size >= ftBytes) {
        float* ft = (float*)d_ws;
        transpose_feats<<<dim3(NN / 64, BB), 256, 0, stream>>>(feats, ft);
        knn_group2<<<(BB * MM) / 4, 256, 0, stream>>>(points, newp, ft, CC, 1, out);
    } else {
        // Fallback: gather straight from [B,C,N] (strided) if ws is too small.
        knn_group2<<<(BB * MM) / 4, 256, 0, stream>>>(points, newp, feats, 1, NN, out);
    }
}

// Round 12
// 58.999 us; speedup vs baseline: 1.3769x; 1.0386x over previous
//
#include <hip/hip_runtime.h>

#define BB 4
#define NN 8192
#define MM 2048
#define CC 64
#define KK 16

// ---------------------------------------------------------------------------
// Kernel 1: transpose features [B,C,N] -> featsT [B,N,C] so per-neighbor
// feature gathers are contiguous 256B rows.
// ---------------------------------------------------------------------------
__global__ __launch_bounds__(256) void transpose_feats(const float* __restrict__ f,
                                                       float* __restrict__ ft) {
    __shared__ float tile[64][65];
    const int b    = blockIdx.y;
    const int n0   = blockIdx.x * 64;
    const int lane = threadIdx.x & 63;
    const int grp  = threadIdx.x >> 6;  // 0..3
    const float* src = f + (size_t)b * CC * NN;
    float* dst       = ft + (size_t)b * NN * CC;
#pragma unroll
    for (int it = 0; it < 16; ++it) {
        const int c = grp + it * 4;                    // channel
        tile[c][lane] = src[c * NN + n0 + lane];       // coalesced along N
    }
    __syncthreads();
#pragma unroll
    for (int it = 0; it < 16; ++it) {
        const int nl = grp + it * 4;                   // local point
        dst[(size_t)(n0 + nl) * CC + lane] = tile[lane][nl];  // coalesced along C
    }
}

// ---------------------------------------------------------------------------
// VERIFIED (round 7, absmax=0): reference rounding = XLA-CPU FPOpFusion::Fast:
//   qq  = fma(qz,qz, fma(qy,qy, qx*qx))
//   pp  = fma(pz,pz, fma(py,py, px*px))
//   dot = fma(qz,pz, fma(qy,py, qx*px))
//   d   = (qq - 2*dot) + pp
// DO NOT CHANGE these two functions. They decide the FINAL ordering (Phase C).
// ---------------------------------------------------------------------------
__device__ __forceinline__ float sq3(float x, float y, float z) {
    return __fmaf_rn(z, z, __fmaf_rn(y, y, __fmul_rn(x, x)));
}
__device__ __forceinline__ float dist32(float qx, float qy, float qz, float qq,
                                        float px, float py, float pz, float pp) {
    float dot = __fmaf_rn(qz, pz, __fmaf_rn(qy, py, __fmul_rn(qx, px)));
    return __fadd_rn(__fsub_rn(qq, __fmul_rn(2.0f, dot)), pp);
}

// Surrogate for SELECTION only (Phases A/B): with nq = -2*q (exact scaling),
//   m2dot = fma(nqz,pz, fma(nqy,py, nqx*px))  ==  -2 * dot  (bit-exact lemma:
//   rounding commutes with *2^k), s = m2dot + pp.
//   |d_exact - (s + qq)| <= ~2e-5  =>  SLACK = 1e-3 makes the candidate set a
//   provable superset of the true top-16. Final order still from dist32.
__device__ __forceinline__ float surr(float nqx, float nqy, float nqz,
                                      float px, float py, float pz, float pp) {
    float m2d = __fmaf_rn(nqz, pz, __fmaf_rn(nqy, py, __fmul_rn(nqx, px)));
    return __fadd_rn(m2d, pp);
}

#define SLACK 1e-3f

// ---------------------------------------------------------------------------
// Kernel 2 (v4): v3 structure (block = 4 queries, 4 waves, disjoint 2048-pt
// ranges, exact-merge tau, launch_bounds(256,8)) with:
//   - surrogate scan in A/B (5 ops/pair vs 7), exact dist32 only for <=64
//     candidates in Phase C  -> identical output, ~22% less scan VALU.
//   - Phase A's 4 bitonic sorts run interleaved (independent shuffle chains).
// ---------------------------------------------------------------------------
__global__ __launch_bounds__(256, 8) void knn_group3(const float* __restrict__ points,
                                                     const float* __restrict__ newp,
                                                     const float* __restrict__ feat,
                                                     const int fsN, const int fsC,
                                                     float* __restrict__ out) {
    const int wave = threadIdx.x >> 6;
    const int lane = threadIdx.x & 63;
    const int qbase = blockIdx.x * 4;               // 4 queries per block
    const int b  = qbase / MM;
    const int m0 = qbase % MM;

    const float* px_ = points + (size_t)b * 3 * NN;
    const float* py_ = px_ + NN;
    const float* pz_ = py_ + NN;
    const float* q_  = newp + (size_t)b * 3 * MM;

    // Only nq = -2*q lives across the scans (q derived back exactly later).
    float nqx[4], nqy[4], nqz[4];
#pragma unroll
    for (int q = 0; q < 4; ++q) {
        nqx[q] = __fmul_rn(-2.0f, q_[m0 + q]);
        nqy[q] = __fmul_rn(-2.0f, q_[MM + m0 + q]);
        nqz[q] = __fmul_rn(-2.0f, q_[2 * MM + m0 + q]);
    }

    const float INF = __int_as_float(0x7f800000);
    const int base = wave * (NN / 4);               // this wave's point range

    __shared__ float s_top[4][4][16];   // [query][wave][rank] (surrogates)
    __shared__ float s_tau[4];          // surrogate-space tau (incl. SLACK)
    __shared__ int   s_cnt[4];
    __shared__ int   s_i[4][64];
    __shared__ int   s_win[4][16];

    // ---- Phase A: per-lane min surrogate over 32 points ----
    float m1[4] = {INF, INF, INF, INF};
#pragma unroll 2
    for (int j4 = 0; j4 < 8; ++j4) {
        const int ib = base + j4 * 256 + lane * 4;
        const float4 vx = *(const float4*)(px_ + ib);
        const float4 vy = *(const float4*)(py_ + ib);
        const float4 vz = *(const float4*)(pz_ + ib);
        const float pxa[4] = {vx.x, vx.y, vx.z, vx.w};
        const float pya[4] = {vy.x, vy.y, vy.z, vy.w};
        const float pza[4] = {vz.x, vz.y, vz.z, vz.w};
#pragma unroll
        for (int e = 0; e < 4; ++e) {
            const float px = pxa[e], py = pya[e], pz = pza[e];
            const float pp = sq3(px, py, pz);
#pragma unroll
            for (int q = 0; q < 4; ++q)
                m1[q] = fminf(m1[q], surr(nqx[q], nqy[q], nqz[q], px, py, pz, pp));
        }
    }

    // ---- 4 bitonic-64 sorts, INTERLEAVED (independent shuffle chains) ----
    {
        float v0 = m1[0], v1 = m1[1], v2 = m1[2], v3 = m1[3];
#pragma unroll
        for (int k = 2; k <= 64; k <<= 1) {
#pragma unroll
            for (int j = k >> 1; j > 0; j >>= 1) {
                const bool keepMin = ((lane & j) == 0) == ((lane & k) == 0);
                const float p0 = __shfl_xor(v0, j, 64);
                const float p1 = __shfl_xor(v1, j, 64);
                const float p2 = __shfl_xor(v2, j, 64);
                const float p3 = __shfl_xor(v3, j, 64);
                v0 = keepMin ? fminf(v0, p0) : fmaxf(v0, p0);
                v1 = keepMin ? fminf(v1, p1) : fmaxf(v1, p1);
                v2 = keepMin ? fminf(v2, p2) : fmaxf(v2, p2);
                v3 = keepMin ? fminf(v3, p3) : fmaxf(v3, p3);
            }
        }
        if (lane < 16) {
            s_top[0][wave][lane] = v0;
            s_top[1][wave][lane] = v1;
            s_top[2][wave][lane] = v2;
            s_top[3][wave][lane] = v3;
        }
    }
    if (threadIdx.x < 4) s_cnt[threadIdx.x] = 0;
    __syncthreads();

    // ---- tau[q]: wave q merges 4 sorted-16 heads -> 16th of 256 minima ----
    {
        const int q = wave;
        float v = s_top[q][lane >> 4][lane & 15];
#pragma unroll
        for (int k = 2; k <= 64; k <<= 1) {
#pragma unroll
            for (int j = k >> 1; j > 0; j >>= 1) {
                const float pv = __shfl_xor(v, j, 64);
                const bool keepMin = ((lane & j) == 0) == ((lane & k) == 0);
                v = keepMin ? fminf(v, pv) : fmaxf(v, pv);
            }
        }
        if (lane == 15) s_tau[q] = v + SLACK;
    }
    __syncthreads();
    float tauS[4];
#pragma unroll
    for (int q = 0; q < 4; ++q) tauS[q] = s_tau[q];

    // ---- Phase B: rescan own range (surrogate), append candidates ----
#pragma unroll 2
    for (int j4 = 0; j4 < 8; ++j4) {
        const int ib = base + j4 * 256 + lane * 4;
        const float4 vx = *(const float4*)(px_ + ib);
        const float4 vy = *(const float4*)(py_ + ib);
        const float4 vz = *(const float4*)(pz_ + ib);
        const float pxa[4] = {vx.x, vx.y, vx.z, vx.w};
        const float pya[4] = {vy.x, vy.y, vy.z, vy.w};
        const float pza[4] = {vz.x, vz.y, vz.z, vz.w};
#pragma unroll
        for (int e = 0; e < 4; ++e) {
            const float px = pxa[e], py = pya[e], pz = pza[e];
            const float pp = sq3(px, py, pz);
#pragma unroll
            for (int q = 0; q < 4; ++q) {
                const float s = surr(nqx[q], nqy[q], nqz[q], px, py, pz, pp);
                if (s <= tauS[q]) {
                    const int pos = atomicAdd(&s_cnt[q], 1);
                    if (pos < 64) s_i[q][pos] = ib + e;
                }
            }
        }
    }
    __syncthreads();

    // ---- Phase C: EXACT dist32 for candidates + bitonic sort (d, idx) ----
    {
        const int q = wave;
        // exact round-trip: q = -0.5 * (-2*q)
        const float qx = __fmul_rn(-0.5f, nqx[q]);
        const float qy = __fmul_rn(-0.5f, nqy[q]);
        const float qz = __fmul_rn(-0.5f, nqz[q]);
        const float qq = sq3(qx, qy, qz);
        const int cnt = min(s_cnt[q], 64);
        float d = INF;
        int idx = 0x7fffffff;
        if (lane < cnt) {
            idx = s_i[q][lane];
            const float px = px_[idx], py = py_[idx], pz = pz_[idx];
            d = dist32(qx, qy, qz, qq, px, py, pz, sq3(px, py, pz));
        }
#pragma unroll
        for (int k = 2; k <= 64; k <<= 1) {
#pragma unroll
            for (int j = k >> 1; j > 0; j >>= 1) {
                const float pd = __shfl_xor(d, j, 64);
                const int   pi = __shfl_xor(idx, j, 64);
                const bool keepMin = ((lane & j) == 0) == ((lane & k) == 0);
                const bool pLess = (pd < d) || (pd == d && pi < idx);
                if (keepMin ? pLess : !pLess) { d = pd; idx = pi; }
            }
        }
        if (lane < KK) s_win[q][lane] = idx;
    }
    __syncthreads();

    // ---- Write: wave g handles channels c = g + 4t; 256B stores per c ----
    const int q2 = lane >> 4;
    const int kk = lane & 15;
    const int idx = s_win[q2][kk];
    const float qxv = __fmul_rn(-0.5f, nqx[q2]);
    const float qyv = __fmul_rn(-0.5f, nqy[q2]);
    const float qzv = __fmul_rn(-0.5f, nqz[q2]);

    float* ob = out + (size_t)b * (3 + CC) * MM * KK + (size_t)(m0 + q2) * KK + kk;
    const size_t chs = (size_t)MM * KK;
    const float* fr = feat + (size_t)b * CC * NN + (size_t)idx * fsN;

#pragma unroll 1
    for (int t = 0; t < 17; ++t) {
        const int c = wave + t * 4;
        if (c < 3 + CC) {
            float val;
            if (c == 0)      val = __fsub_rn(px_[idx], qxv);
            else if (c == 1) val = __fsub_rn(py_[idx], qyv);
            else if (c == 2) val = __fsub_rn(pz_[idx], qzv);
            else             val = fr[(size_t)(c - 3) * fsC];
            ob[(size_t)c * chs] = val;
        }
    }
}

extern "C" void kernel_launch(void* const* d_in, const int* in_sizes, int n_in,
                              void* d_out, int out_size, void* d_ws, size_t ws_size,
                              hipStream_t stream) {
    const float* points = (const float*)d_in[0];
    const float* newp   = (const float*)d_in[1];
    const float* feats  = (const float*)d_in[2];
    float* out = (float*)d_out;

    const size_t ftBytes = (size_t)BB * NN * CC * sizeof(float);
    if (ws_size >= ftBytes) {
        float* ft = (float*)d_ws;
        transpose_feats<<<dim3(NN / 64, BB), 256, 0, stream>>>(feats, ft);
        knn_group3<<<(BB * MM) / 4, 256, 0, stream>>>(points, newp, ft, CC, 1, out);
    } else {
        // Fallback: gather straight from [B,C,N] (strided) if ws is too small.
        knn_group3<<<(BB * MM) / 4, 256, 0, stream>>>(points, newp, feats, 1, NN, out);
    }
}